// Round 23
// baseline (875.225 us; speedup 1.0000x reference)
//
#include <hip/hip_runtime.h>

#define N_NODES 200000
#define N_EDGES 800000
#define NODE_IN 133
#define EDGE_IN 14
#define HID 128
#define NUM_GRAPHS 4096

#define SCAN_CHUNK 2048
#define SCAN_NBLK ((N_NODES + SCAN_CHUNK - 1) / SCAN_CHUNK)  // 98

#define MT 64    // M tile rows for k_xw/k_init3/k_node
#define MT2 128  // M tile rows for k_msg (512 threads, 8 waves)

// K geometry per GEMM (padded K, LDS/WT row stride in elements)
#define K1_PAD 160
#define K1_STRIDE 168
#define K2_PAD 128
#define K2_STRIDE 136
#define K3_PAD 288
#define K3_STRIDE 296    // WT3 global row stride == k_node LDS stride
#define KE_PAD 32        // k_init3 ea K (14 used, zero-padded)
#define KE_STRIDE 40

typedef unsigned short u16;
typedef unsigned char u8;
typedef short bf16x8 __attribute__((ext_vector_type(8)));
typedef float f32x4 __attribute__((ext_vector_type(4)));
typedef unsigned uintx2 __attribute__((ext_vector_type(2)));
typedef unsigned uintx4 __attribute__((ext_vector_type(4)));

__device__ __forceinline__ float bu2f(unsigned s) {
    return __uint_as_float(s << 16);
}
__device__ __forceinline__ u16 f2bu(float f) {
    unsigned u = __float_as_uint(f);
    return (u16)((u + 0x7FFFu + ((u >> 16) & 1u)) >> 16);  // RNE
}
// truncating f32->bf16 (1 op). Use ONLY where inputs are already fp8-coarse.
__device__ __forceinline__ u16 f2bt(float f) {
    return (u16)(__float_as_uint(f) >> 16);
}
// non-temporal (streaming) load/store helpers — cache-policy hint only
__device__ __forceinline__ uint4 ntload4(const void* p) {
    const uintx4 v = __builtin_nontemporal_load((const uintx4*)p);
    uint4 o; o.x = v.x; o.y = v.y; o.z = v.z; o.w = v.w;
    return o;
}
__device__ __forceinline__ uint2 ntload2(const void* p) {
    const uintx2 v = __builtin_nontemporal_load((const uintx2*)p);
    uint2 o; o.x = v.x; o.y = v.y;
    return o;
}
__device__ __forceinline__ void ntstore2(void* p, uint2 v) {
    uintx2 t; t.x = v.x; t.y = v.y;
    __builtin_nontemporal_store(t, (uintx2*)p);
}
// ---------------- fp8 e4m3 (OCP), non-negative post-ReLU values -----------
__device__ __forceinline__ float e42f(unsigned b) {
    unsigned E = (b >> 4) & 0xF, M = b & 7u;
    if (E == 0) return (float)M * 0.001953125f;  // M * 2^-9
    return __uint_as_float(((E - 7u + 127u) << 23) | (M << 20));
}
__device__ __forceinline__ u8 f2e4(float f) {
    if (!(f > 0.f)) return 0;
    if (f >= 448.f) return 0x7E;
    unsigned u = __float_as_uint(f);
    int e = (int)((u >> 23) & 0xFF) - 127;
    if (e < -6) {
        int q = (int)rintf(f * 512.f);
        return (u8)q;
    }
    unsigned m = u & 0x7FFFFF;
    unsigned keep = m >> 20, rem = m & 0xFFFFF;
    keep += (rem > 0x80000u || (rem == 0x80000u && (keep & 1u))) ? 1u : 0u;
    unsigned E = (unsigned)(e + 7);
    if (keep == 8u) { keep = 0u; E++; }
    return (u8)((E << 4) | keep);
}

// ---------------- HW fp8 convert (gfx950 OCP) with software fallback -------
#if defined(__has_builtin)
#if __has_builtin(__builtin_amdgcn_cvt_f32_fp8) && __has_builtin(__builtin_amdgcn_cvt_pk_fp8_f32)
#define HW_FP8 1
#endif
#endif

#if defined(HW_FP8)
// sel must be a compile-time constant
#define FP8_DEC(dw, s) __builtin_amdgcn_cvt_f32_fp8((int)(dw), (s))
__device__ __forceinline__ unsigned fp8_pk(float a, float b) {
    a = fminf(fmaxf(a, 0.f), 448.f);  // ReLU + sat (matches sw path)
    b = fminf(fmaxf(b, 0.f), 448.f);
    return (unsigned)__builtin_amdgcn_cvt_pk_fp8_f32(a, b, 0, false) & 0xFFFFu;
}
#else
#define FP8_DEC(dw, s) e42f(((dw) >> (8 * (s))) & 0xFFu)
__device__ __forceinline__ unsigned fp8_pk(float a, float b) {
    return (unsigned)f2e4(a) | ((unsigned)f2e4(b) << 8);
}
#endif

__device__ __forceinline__ int clampi(int v, int hi) {
    return v < 0 ? 0 : (v >= hi ? hi - 1 : v);
}

__device__ __forceinline__ void acc16(float* a, const uint4 v) {
    a[0]  += FP8_DEC(v.x, 0); a[1]  += FP8_DEC(v.x, 1);
    a[2]  += FP8_DEC(v.x, 2); a[3]  += FP8_DEC(v.x, 3);
    a[4]  += FP8_DEC(v.y, 0); a[5]  += FP8_DEC(v.y, 1);
    a[6]  += FP8_DEC(v.y, 2); a[7]  += FP8_DEC(v.y, 3);
    a[8]  += FP8_DEC(v.z, 0); a[9]  += FP8_DEC(v.z, 1);
    a[10] += FP8_DEC(v.z, 2); a[11] += FP8_DEC(v.z, 3);
    a[12] += FP8_DEC(v.w, 0); a[13] += FP8_DEC(v.w, 1);
    a[14] += FP8_DEC(v.w, 2); a[15] += FP8_DEC(v.w, 3);
}

// ---------------------------------------------------------------------------
// Weight prep (single launch): WT[n][k] = bf16(W[k][n]), k < K else 0.
// ---------------------------------------------------------------------------
__global__ __launch_bounds__(256) void k_prep3(const float* __restrict__ W1,
                                               const float* __restrict__ W2,
                                               const float* __restrict__ W3,
                                               u16* __restrict__ WT1,
                                               u16* __restrict__ WT2,
                                               u16* __restrict__ WT3) {
    int idx = blockIdx.x * 256 + threadIdx.x;
    const int n1 = HID * K1_STRIDE, n2 = HID * K2_STRIDE, n3 = HID * K3_STRIDE;
    if (idx < n1) {
        const int n = idx / K1_STRIDE, k = idx % K1_STRIDE;
        WT1[idx] = (k < NODE_IN + EDGE_IN) ? f2bu(W1[k * HID + n]) : (u16)0;
    } else if ((idx -= n1) < n2) {
        const int n = idx / K2_STRIDE, k = idx % K2_STRIDE;
        WT2[idx] = (k < HID) ? f2bu(W2[k * HID + n]) : (u16)0;
    } else if ((idx -= n2) < n3) {
        const int n = idx / K3_STRIDE, k = idx % K3_STRIDE;
        WT3[idx] = (k < NODE_IN + HID) ? f2bu(W3[k * HID + n]) : (u16)0;
    }
}

// ---------------------------------------------------------------------------
// CSR build: histogram -> exclusive scan -> atomic-cursor placement.
// Edge state space is RELABELED into dst-sorted order: j <-> eidx[j].
// ---------------------------------------------------------------------------
__global__ __launch_bounds__(256) void k_hist(const int* __restrict__ dst,
                                              int* __restrict__ cnt) {
    const int e = blockIdx.x * 256 + threadIdx.x;
    if (e < N_EDGES) atomicAdd(&cnt[clampi(dst[e], N_NODES)], 1);
}

__global__ __launch_bounds__(256) void k_scan1(const int* __restrict__ cnt,
                                               int* __restrict__ local,
                                               int* __restrict__ partial) {
    __shared__ int tsum[256];
    const int b = blockIdx.x, t = threadIdx.x;
    const int base = b * SCAN_CHUNK + t * 8;
    int v[8];
    int s = 0;
#pragma unroll
    for (int i = 0; i < 8; i++) {
        const int idx = base + i;
        v[i] = (idx < N_NODES) ? cnt[idx] : 0;
        s += v[i];
    }
    tsum[t] = s;
    __syncthreads();
    for (int ofs = 1; ofs < 256; ofs <<= 1) {
        const int add = (t >= ofs) ? tsum[t - ofs] : 0;
        __syncthreads();
        tsum[t] += add;
        __syncthreads();
    }
    int excl = (t == 0) ? 0 : tsum[t - 1];
    if (t == 255) partial[b] = tsum[255];
#pragma unroll
    for (int i = 0; i < 8; i++) {
        const int idx = base + i;
        if (idx < N_NODES) local[idx] = excl;
        excl += v[i];
    }
}

__global__ __launch_bounds__(256) void k_scan2(int* __restrict__ partial) {
    __shared__ int s[256];
    const int t = threadIdx.x;
    s[t] = (t < SCAN_NBLK) ? partial[t] : 0;
    __syncthreads();
    for (int ofs = 1; ofs < 256; ofs <<= 1) {
        const int add = (t >= ofs) ? s[t - ofs] : 0;
        __syncthreads();
        s[t] += add;
        __syncthreads();
    }
    if (t < SCAN_NBLK) partial[t] = (t == 0) ? 0 : s[t - 1];
}

__global__ __launch_bounds__(256) void k_scan3(const int* __restrict__ local,
                                               const int* __restrict__ partial,
                                               int* __restrict__ row_ptr,
                                               int* __restrict__ cursor) {
    const int idx = blockIdx.x * 256 + threadIdx.x;
    if (idx <= N_NODES) {
        const int v = (idx == N_NODES) ? N_EDGES
                                       : local[idx] + partial[idx / SCAN_CHUNK];
        row_ptr[idx] = v;
        if (idx < N_NODES) cursor[idx] = v;
    }
}

// placement + inverse permutation in one pass
__global__ __launch_bounds__(256) void k_place(const int* __restrict__ dst,
                                               int* __restrict__ cursor,
                                               int* __restrict__ eidx,
                                               int* __restrict__ inv) {
    const int e = blockIdx.x * 256 + threadIdx.x;
    if (e < N_EDGES) {
        const int slot = atomicAdd(&cursor[clampi(dst[e], N_NODES)], 1);
        eidx[slot] = e;
        inv[e] = slot;
    }
}

// merged remap + ea pack: one eidx read per sorted edge
__global__ __launch_bounds__(256) void k_setup(const int* __restrict__ eidx,
                                               const int* __restrict__ src,
                                               const int* __restrict__ rev,
                                               const int* __restrict__ inv,
                                               const float* __restrict__ ea,
                                               int* __restrict__ src_d,
                                               int* __restrict__ rev_d,
                                               u16* __restrict__ ea_d) {
    const int j = blockIdx.x * 256 + threadIdx.x;
    if (j >= N_EDGES) return;
    const int e = clampi(eidx[j], N_EDGES);
    src_d[j] = src[e];
    rev_d[j] = inv[clampi(rev[e], N_EDGES)];
    const float2* er = (const float2*)(ea + (size_t)e * EDGE_IN);
    u16 v[16];
#pragma unroll
    for (int k = 0; k < 7; k++) {
        const float2 u = er[k];
        v[2 * k] = f2bu(u.x);
        v[2 * k + 1] = f2bu(u.y);
    }
    v[14] = 0; v[15] = 0;
    uint4 o1, o2;
    o1.x = (unsigned)v[0] | ((unsigned)v[1] << 16);
    o1.y = (unsigned)v[2] | ((unsigned)v[3] << 16);
    o1.z = (unsigned)v[4] | ((unsigned)v[5] << 16);
    o1.w = (unsigned)v[6] | ((unsigned)v[7] << 16);
    o2.x = (unsigned)v[8] | ((unsigned)v[9] << 16);
    o2.y = (unsigned)v[10] | ((unsigned)v[11] << 16);
    o2.z = (unsigned)v[12] | ((unsigned)v[13] << 16);
    o2.w = 0;
    uint4* dstp = (uint4*)(ea_d + (size_t)j * 16);
    dstp[0] = o1;
    dstp[1] = o2;
}

// ---------------------------------------------------------------------------
// K2 (streaming gather): node_sum[n] (fp8) = sum over contiguous sorted rows.
// 8 threads/node, 16 channels each; h rows streamed non-temporally.
// ---------------------------------------------------------------------------
__global__ __launch_bounds__(256) void k_gather(const u8* __restrict__ h,
                                                const int* __restrict__ row_ptr,
                                                u8* __restrict__ node_sum) {
    const long long idx = (long long)blockIdx.x * 256 + threadIdx.x;
    const int n = (int)(idx >> 3);
    if (n >= N_NODES) return;
    const int c16 = (int)(idx & 7) << 4;
    const int beg = row_ptr[n], end = row_ptr[n + 1];
    float a[16];
#pragma unroll
    for (int i = 0; i < 16; i++) a[i] = 0.f;
    int j = beg;
    for (; j + 4 <= end; j += 4) {
        const uint4 v0 = ntload4(h + (long long)j * HID + c16);
        const uint4 v1 = ntload4(h + (long long)(j + 1) * HID + c16);
        const uint4 v2 = ntload4(h + (long long)(j + 2) * HID + c16);
        const uint4 v3 = ntload4(h + (long long)(j + 3) * HID + c16);
        acc16(a, v0); acc16(a, v1); acc16(a, v2); acc16(a, v3);
    }
    for (; j < end; j++) {
        const uint4 v = ntload4(h + (long long)j * HID + c16);
        acc16(a, v);
    }
    uint4 o;
    o.x = fp8_pk(a[0], a[1])   | (fp8_pk(a[2], a[3])   << 16);
    o.y = fp8_pk(a[4], a[5])   | (fp8_pk(a[6], a[7])   << 16);
    o.z = fp8_pk(a[8], a[9])   | (fp8_pk(a[10], a[11]) << 16);
    o.w = fp8_pk(a[12], a[13]) | (fp8_pk(a[14], a[15]) << 16);
    *(uint4*)(node_sum + (long long)n * HID + c16) = o;
}

// ---------------------------------------------------------------------------
// MFMA geometry: a-frag lane holds A[lane&15][(lane>>4)*8 + i];
// C/D: col = lane&15, row = (lane>>4)*4 + reg.
// k_xw/k_init3: 4 waves (2Mx2N). k_msg: 8 waves (4Mx2N), 128-row tiles.
// k_node: 8 waves (2Mx4N), fused final aggregation.
// ---------------------------------------------------------------------------

// K1a: xw[n] = x[n] @ W1x  (per-NODE GEMM; A cols 133..159 zeroed)
__global__ __launch_bounds__(256) void k_xw(const float* __restrict__ x,
                                            const u16* __restrict__ WT1,
                                            u16* __restrict__ xw) {
    __shared__ u16 A[MT * K1_STRIDE];
    const int n0 = blockIdx.x * MT;
    const int t = threadIdx.x;
    const int lane = t & 63, wv = t >> 6;
    for (int rr = 0; rr < 16; rr++) {
        const int row = wv * 16 + rr;
        const int n = n0 + row;
        const float* xr = x + (size_t)n * NODE_IN;
        u16* dstr = &A[row * K1_STRIDE];
        dstr[lane] = f2bu(xr[lane]);                 // k 0..63
        dstr[64 + lane] = f2bu(xr[64 + lane]);       // k 64..127
        if (lane < 5) dstr[128 + lane] = f2bu(xr[128 + lane]);  // 128..132
        if (lane < K1_PAD - NODE_IN) dstr[NODE_IN + lane] = 0;  // 133..159
    }
    __syncthreads();

    const int wm = wv & 1, wn = wv >> 1;
    const int lr = lane & 15, lk = (lane >> 4) * 8;
    f32x4 acc[2][4];
#pragma unroll
    for (int m = 0; m < 2; m++)
#pragma unroll
        for (int n = 0; n < 4; n++) acc[m][n] = (f32x4){0.f, 0.f, 0.f, 0.f};

    const int ar0 = (wm * 32 + lr) * K1_STRIDE + lk;
#pragma unroll
    for (int ks = 0; ks < K1_PAD / 32; ks++) {
        const int kk = ks * 32;
        const bf16x8 a0 = *(const bf16x8*)&A[ar0 + kk];
        const bf16x8 a1 = *(const bf16x8*)&A[ar0 + 16 * K1_STRIDE + kk];
#pragma unroll
        for (int n = 0; n < 4; n++) {
            const bf16x8 b = *(const bf16x8*)&WT1[(size_t)(wn * 64 + n * 16 + lr) * K1_STRIDE + kk + lk];
            acc[0][n] = __builtin_amdgcn_mfma_f32_16x16x32_bf16(a0, b, acc[0][n], 0, 0, 0);
            acc[1][n] = __builtin_amdgcn_mfma_f32_16x16x32_bf16(a1, b, acc[1][n], 0, 0, 0);
        }
    }

    const int lr4 = lane >> 4;
#pragma unroll
    for (int n = 0; n < 4; n++) {
        const int col = wn * 64 + n * 16 + lr;
#pragma unroll
        for (int m = 0; m < 2; m++)
#pragma unroll
            for (int j = 0; j < 4; j++) {
                const int nd = n0 + wm * 32 + m * 16 + lr4 * 4 + j;
                xw[(size_t)nd * HID + col] = f2bu(acc[m][n][j]);
            }
    }
}

// K1b (MFMA): h0[j] = relu(xw[src_d[j]] + ea_d[j]@W1e + b1) -> fp8.
// ea matvec on the matrix pipe; xw row PREFETCHED; W1e staged from WT1.
__global__ __launch_bounds__(256) void k_init3(const u16* __restrict__ xw,
                                               const u16* __restrict__ ea_d,
                                               const u16* __restrict__ WT1,
                                               const float* __restrict__ b1,
                                               const int* __restrict__ src_d,
                                               u8* __restrict__ h0) {
    __shared__ u16 Aea[MT * KE_STRIDE];       // 5120 B
    __shared__ u16 W1e[HID * KE_PAD];         // [n][k], 8192 B
    __shared__ u16 Sacc[MT * K2_STRIDE];      // 17408 B staging
    __shared__ float b1s[HID];
    const int e0 = blockIdx.x * MT;
    const int t = threadIdx.x;

    // prefetch phase-2 operands (consumed after 2 barriers)
    const int prow = t >> 2, pj = t & 3;
    const int ps = clampi(src_d[e0 + prow], N_NODES);
    uint4 xv[4];
#pragma unroll
    for (int q = 0; q < 4; q++)
        xv[q] = *(const uint4*)(xw + (size_t)ps * HID + pj * 32 + q * 8);

    for (int i = t; i < HID * KE_PAD; i += 256) {
        const int n = i >> 5, k = i & 31;
        W1e[i] = (k < EDGE_IN) ? WT1[n * K1_STRIDE + NODE_IN + k] : (u16)0;
    }
    if (t < HID) b1s[t] = b1[t];
    {   // ea tile: 4 threads/row, 8B each; pad 16..31 zeroed
        const int row = t >> 2, q = t & 3;
        const uint2 v = *(const uint2*)(ea_d + (size_t)(e0 + row) * 16 + q * 4);
        *(uint2*)&Aea[row * KE_STRIDE + q * 4] = v;
        uint2 z; z.x = 0; z.y = 0;
        *(uint2*)&Aea[row * KE_STRIDE + 16 + q * 4] = z;
    }
    __syncthreads();

    const int lane = t & 63, wid = t >> 6;
    const int wm = wid & 1, wn = wid >> 1;
    const int lr = lane & 15, lk = (lane >> 4) * 8;
    f32x4 acc[2][4];
#pragma unroll
    for (int m = 0; m < 2; m++)
#pragma unroll
        for (int n = 0; n < 4; n++) acc[m][n] = (f32x4){0.f, 0.f, 0.f, 0.f};

    {
        const bf16x8 a0 = *(const bf16x8*)&Aea[(wm * 32 + lr) * KE_STRIDE + lk];
        const bf16x8 a1 = *(const bf16x8*)&Aea[(wm * 32 + 16 + lr) * KE_STRIDE + lk];
#pragma unroll
        for (int n = 0; n < 4; n++) {
            const bf16x8 b = *(const bf16x8*)&W1e[(wn * 64 + n * 16 + lr) * KE_PAD + lk];
            acc[0][n] = __builtin_amdgcn_mfma_f32_16x16x32_bf16(a0, b, acc[0][n], 0, 0, 0);
            acc[1][n] = __builtin_amdgcn_mfma_f32_16x16x32_bf16(a1, b, acc[1][n], 0, 0, 0);
        }
    }

    // stage product bf16 -> Sacc[row][col]
    const int lr4 = lane >> 4;
#pragma unroll
    for (int n = 0; n < 4; n++) {
        const int col = wn * 64 + n * 16 + lr;
#pragma unroll
        for (int m = 0; m < 2; m++)
#pragma unroll
            for (int j = 0; j < 4; j++) {
                const int row = wm * 32 + m * 16 + lr4 * 4 + j;
                Sacc[row * K2_STRIDE + col] = f2bu(acc[m][n][j]);
            }
    }
    __syncthreads();

    // phase 2: coalesced, thread = (row, 32-ch chunk)
    const long long e = e0 + prow;
#pragma unroll
    for (int q = 0; q < 4; q++) {
        const int c8 = pj * 32 + q * 8;
        const uint4 sv = *(const uint4*)&Sacc[prow * K2_STRIDE + c8];  // 8 bf16
        const float4 ba = *(const float4*)&b1s[c8];
        const float4 bbv = *(const float4*)&b1s[c8 + 4];
        const float v0 = bu2f(sv.x & 0xFFFFu) + bu2f(xv[q].x & 0xFFFFu) + ba.x;
        const float v1 = bu2f(sv.x >> 16)     + bu2f(xv[q].x >> 16)     + ba.y;
        const float v2 = bu2f(sv.y & 0xFFFFu) + bu2f(xv[q].y & 0xFFFFu) + ba.z;
        const float v3 = bu2f(sv.y >> 16)     + bu2f(xv[q].y >> 16)     + ba.w;
        const float v4 = bu2f(sv.z & 0xFFFFu) + bu2f(xv[q].z & 0xFFFFu) + bbv.x;
        const float v5 = bu2f(sv.z >> 16)     + bu2f(xv[q].z >> 16)     + bbv.y;
        const float v6 = bu2f(sv.w & 0xFFFFu) + bu2f(xv[q].w & 0xFFFFu) + bbv.z;
        const float v7 = bu2f(sv.w >> 16)     + bu2f(xv[q].w >> 16)     + bbv.w;
        uint2 o;
        o.x = fp8_pk(v0, v1) | (fp8_pk(v2, v3) << 16);
        o.y = fp8_pk(v4, v5) | (fp8_pk(v6, v7) << 16);
        *(uint2*)(h0 + e * HID + c8) = o;
    }
}

// K3: hn[j] = relu(h0[j] + (node_sum[src_d[j]] - h[rev_d[j]]) @ W2 + b2)
// 512 threads, 8 waves (4M x 2N), 128-edge tile. ns is fp8; h0 prefetched
// non-temporally (streamed once); hn stored non-temporally.
__global__ __launch_bounds__(512) void k_msg_mfma(const u8* __restrict__ ns,
                                                  const u8* __restrict__ h,
                                                  const u8* __restrict__ h0g,
                                                  const u16* __restrict__ WT2,
                                                  const float* __restrict__ b2,
                                                  const int* __restrict__ src_d,
                                                  const int* __restrict__ rev_d,
                                                  u8* __restrict__ hn) {
    __shared__ u16 A[MT2 * K2_STRIDE];  // 34816 B
    __shared__ float b2s[HID];
    const int e0 = blockIdx.x * MT2;
    const int t = threadIdx.x;

    // prefetch phase-2 h0 row chunks (stream; consumed after 2 barriers)
    const int prow = t >> 2, pj = t & 3;   // prow 0..127
    const long long pe = e0 + prow;
    uint2 h0v[4];
#pragma unroll
    for (int q = 0; q < 4; q++)
        h0v[q] = ntload2(h0g + pe * HID + pj * 32 + q * 8);

    if (t < HID) b2s[t] = b2[t];
    {   // builder: 4 threads/row, 32 channels each (all fp8 inputs)
        const int s = clampi(src_d[e0 + prow], N_NODES);
        const int r = clampi(rev_d[e0 + prow], N_EDGES);
        const u8* nsr = ns + (size_t)s * HID + pj * 32;
        const u8* hr = h + (size_t)r * HID + pj * 32;
        u16* dstr = &A[prow * K2_STRIDE + pj * 32];
#pragma unroll
        for (int q = 0; q < 4; q++) {
            const uint2 nv = *(const uint2*)(nsr + q * 8);  // 8 fp8
            const uint2 hv = *(const uint2*)(hr + q * 8);   // 8 fp8
            union { bf16x8 v; u16 s[8]; } o;
            o.s[0] = f2bt(FP8_DEC(nv.x, 0) - FP8_DEC(hv.x, 0));
            o.s[1] = f2bt(FP8_DEC(nv.x, 1) - FP8_DEC(hv.x, 1));
            o.s[2] = f2bt(FP8_DEC(nv.x, 2) - FP8_DEC(hv.x, 2));
            o.s[3] = f2bt(FP8_DEC(nv.x, 3) - FP8_DEC(hv.x, 3));
            o.s[4] = f2bt(FP8_DEC(nv.y, 0) - FP8_DEC(hv.y, 0));
            o.s[5] = f2bt(FP8_DEC(nv.y, 1) - FP8_DEC(hv.y, 1));
            o.s[6] = f2bt(FP8_DEC(nv.y, 2) - FP8_DEC(hv.y, 2));
            o.s[7] = f2bt(FP8_DEC(nv.y, 3) - FP8_DEC(hv.y, 3));
            *(bf16x8*)(dstr + q * 8) = o.v;
        }
    }
    __syncthreads();

    const int lane = t & 63, wid = t >> 6;   // 8 waves
    const int wm = wid & 3, wn = wid >> 2;   // 4 in M, 2 in N
    const int lr = lane & 15, lk = (lane >> 4) * 8;
    f32x4 acc[2][4];
#pragma unroll
    for (int m = 0; m < 2; m++)
#pragma unroll
        for (int n = 0; n < 4; n++) acc[m][n] = (f32x4){0.f, 0.f, 0.f, 0.f};

    const int ar0 = (wm * 32 + lr) * K2_STRIDE + lk;
#pragma unroll
    for (int ks = 0; ks < K2_PAD / 32; ks++) {
        const int kk = ks * 32;
        const bf16x8 a0 = *(const bf16x8*)&A[ar0 + kk];
        const bf16x8 a1 = *(const bf16x8*)&A[ar0 + 16 * K2_STRIDE + kk];
#pragma unroll
        for (int n = 0; n < 4; n++) {
            const bf16x8 b = *(const bf16x8*)&WT2[(size_t)(wn * 64 + n * 16 + lr) * K2_STRIDE + kk + lk];
            acc[0][n] = __builtin_amdgcn_mfma_f32_16x16x32_bf16(a0, b, acc[0][n], 0, 0, 0);
            acc[1][n] = __builtin_amdgcn_mfma_f32_16x16x32_bf16(a1, b, acc[1][n], 0, 0, 0);
        }
    }

    __syncthreads();  // A's builder data fully consumed
    const int lr4 = lane >> 4;
#pragma unroll
    for (int n = 0; n < 4; n++) {
        const int col = wn * 64 + n * 16 + lr;
#pragma unroll
        for (int m = 0; m < 2; m++)
#pragma unroll
            for (int j = 0; j < 4; j++) {
                const int row = wm * 32 + m * 16 + lr4 * 4 + j;
                A[row * K2_STRIDE + col] = f2bt(acc[m][n][j]);
            }
    }
    __syncthreads();

#pragma unroll
    for (int q = 0; q < 4; q++) {
        const int c8 = pj * 32 + q * 8;
        const uint4 sv = *(const uint4*)&A[prow * K2_STRIDE + c8];  // 8 bf16
        const float4 ba = *(const float4*)&b2s[c8];
        const float4 bbv = *(const float4*)&b2s[c8 + 4];
        const float v0 = bu2f(sv.x & 0xFFFFu) + FP8_DEC(h0v[q].x, 0) + ba.x;
        const float v1 = bu2f(sv.x >> 16)     + FP8_DEC(h0v[q].x, 1) + ba.y;
        const float v2 = bu2f(sv.y & 0xFFFFu) + FP8_DEC(h0v[q].x, 2) + ba.z;
        const float v3 = bu2f(sv.y >> 16)     + FP8_DEC(h0v[q].x, 3) + ba.w;
        const float v4 = bu2f(sv.z & 0xFFFFu) + FP8_DEC(h0v[q].y, 0) + bbv.x;
        const float v5 = bu2f(sv.z >> 16)     + FP8_DEC(h0v[q].y, 1) + bbv.y;
        const float v6 = bu2f(sv.w & 0xFFFFu) + FP8_DEC(h0v[q].y, 2) + bbv.z;
        const float v7 = bu2f(sv.w >> 16)     + FP8_DEC(h0v[q].y, 3) + bbv.w;
        uint2 o;
        o.x = fp8_pk(v0, v1) | (fp8_pk(v2, v3) << 16);
        o.y = fp8_pk(v4, v5) | (fp8_pk(v6, v7) << 16);
        ntstore2(hn + pe * HID + c8, o);
    }
}

// K5 (FUSED final aggregation + node GEMM):
// node_attr[n] = relu(concat(x[n], sum_{j in csr[n]} h[j]) @ W3 + b3)
// 512 threads, 8 waves (2M x 4N), single-phase full-K tile (64 x 296 LDS).
__global__ __launch_bounds__(512) void k_node_mfma(const float* __restrict__ x,
                                                   const u8* __restrict__ h,
                                                   const int* __restrict__ row_ptr,
                                                   const u16* __restrict__ WT3,
                                                   const float* __restrict__ b3,
                                                   u16* __restrict__ node_attr) {
    __shared__ u16 A[MT * K3_STRIDE];  // 37888 B
    const int n0 = blockIdx.x * MT;
    const int t = threadIdx.x;
    const int lane = t & 63, wv = t >> 6;       // 8 waves
    const int wm = wv & 1, wn = wv >> 1;        // 2 in M, 4 in N
    const int lr = lane & 15, lk = (lane >> 4) * 8;

    {   // phase A: vmsg summation (fused gather). lane = sub-node*8 + chunk
        const int vrow = wv * 8 + (lane >> 3);
        const int vn = n0 + vrow;
        const int c16 = (lane & 7) << 4;
        const int beg = row_ptr[vn], end = row_ptr[vn + 1];
        float a[16];
#pragma unroll
        for (int i = 0; i < 16; i++) a[i] = 0.f;
        int j = beg;
        for (; j + 4 <= end; j += 4) {
            const uint4 v0 = ntload4(h + (long long)j * HID + c16);
            const uint4 v1 = ntload4(h + (long long)(j + 1) * HID + c16);
            const uint4 v2 = ntload4(h + (long long)(j + 2) * HID + c16);
            const uint4 v3 = ntload4(h + (long long)(j + 3) * HID + c16);
            acc16(a, v0); acc16(a, v1); acc16(a, v2); acc16(a, v3);
        }
        for (; j < end; j++) {
            const uint4 v = ntload4(h + (long long)j * HID + c16);
            acc16(a, v);
        }
        u16* vd = &A[vrow * K3_STRIDE + NODE_IN + c16];  // cols 133..260
#pragma unroll
        for (int i = 0; i < 16; i++) vd[i] = f2bt(a[i]);
    }

    // phase B: x columns + zero pad (8 rows per wave, 64 lanes)
    for (int rr = 0; rr < 8; rr++) {
        const int row = wv * 8 + rr;
        const int n = n0 + row;
        const float* xr = x + (size_t)n * NODE_IN;
        u16* dstr = &A[row * K3_STRIDE];
        dstr[lane] = f2bu(xr[lane]);                 // k 0..63
        dstr[64 + lane] = f2bu(xr[64 + lane]);       // k 64..127
        if (lane < 5) dstr[128 + lane] = f2bu(xr[128 + lane]);  // 128..132
        if (lane < K3_PAD - (NODE_IN + HID))         // 261..287
            dstr[NODE_IN + HID + lane] = 0;
    }
    __syncthreads();

    f32x4 acc[2][2];
#pragma unroll
    for (int m = 0; m < 2; m++)
#pragma unroll
        for (int n = 0; n < 2; n++) acc[m][n] = (f32x4){0.f, 0.f, 0.f, 0.f};
    const int ar0 = (wm * 32 + lr) * K3_STRIDE + lk;

    for (int ks = 0; ks < K3_PAD / 32; ks++) {       // 9 steps
        const int kk = ks * 32;
        const bf16x8 a0 = *(const bf16x8*)&A[ar0 + kk];
        const bf16x8 a1 = *(const bf16x8*)&A[ar0 + 16 * K3_STRIDE + kk];
#pragma unroll
        for (int n = 0; n < 2; n++) {
            const bf16x8 b = *(const bf16x8*)&WT3[(size_t)(wn * 32 + n * 16 + lr) * K3_STRIDE + kk + lk];
            acc[0][n] = __builtin_amdgcn_mfma_f32_16x16x32_bf16(a0, b, acc[0][n], 0, 0, 0);
            acc[1][n] = __builtin_amdgcn_mfma_f32_16x16x32_bf16(a1, b, acc[1][n], 0, 0, 0);
        }
    }

    const int lr4 = lane >> 4;
#pragma unroll
    for (int n = 0; n < 2; n++) {
        const int col = wn * 32 + n * 16 + lr;
        const float bias = b3[col];
#pragma unroll
        for (int m = 0; m < 2; m++)
#pragma unroll
            for (int j = 0; j < 4; j++) {
                const int nd = n0 + wm * 32 + m * 16 + lr4 * 4 + j;
                float v = acc[m][n][j] + bias;
                node_attr[(size_t)nd * HID + col] = f2bu(v > 0.f ? v : 0.f);
            }
    }
}

// ---------------------------------------------------------------------------
// K6: out[g] = mean over the graph's contiguous node range (bf16 node_attr).
// ---------------------------------------------------------------------------
__global__ __launch_bounds__(128) void k_pool2(const u16* __restrict__ node_attr,
                                               const int* __restrict__ batch,
                                               float* __restrict__ out) {
    const int g = blockIdx.x;
    __shared__ int lo_s, hi_s;
    if (threadIdx.x == 0) {
        int lo = 0, hi = N_NODES;
        while (lo < hi) { int mid = (lo + hi) >> 1; if (batch[mid] < g) lo = mid + 1; else hi = mid; }
        lo_s = lo;
        int lo2 = lo, hi2 = N_NODES;
        while (lo2 < hi2) { int mid = (lo2 + hi2) >> 1; if (batch[mid] <= g) lo2 = mid + 1; else hi2 = mid; }
        hi_s = lo2;
    }
    __syncthreads();
    const int lo = lo_s, hi = hi_s;
    float acc = 0.f;
    for (int n = lo; n < hi; n++)
        acc += bu2f(node_attr[(size_t)n * HID + threadIdx.x]);
    const float cnt = (hi > lo) ? (float)(hi - lo) : 1.f;
    out[(size_t)g * HID + threadIdx.x] = acc / cnt;
}

// ---------------------------------------------------------------------------
extern "C" void kernel_launch(void* const* d_in, const int* in_sizes, int n_in,
                              void* d_out, int out_size, void* d_ws, size_t ws_size,
                              hipStream_t stream) {
    const float* x   = (const float*)d_in[0];
    const float* ea  = (const float*)d_in[1];
    const float* W1  = (const float*)d_in[2];
    const float* b1  = (const float*)d_in[3];
    const float* W2  = (const float*)d_in[4];
    const float* b2  = (const float*)d_in[5];
    const float* W3  = (const float*)d_in[6];
    const float* b3  = (const float*)d_in[7];
    const int*   ei  = (const int*)d_in[8];
    const int*   src = ei;
    const int*   dst = ei + N_EDGES;
    const int*   rev = (const int*)d_in[9];
    const int*   bat = (const int*)d_in[10];

    char* ws = (char*)d_ws;
    size_t off = 0;
    auto alloc = [&](size_t bytes) -> void* {
        void* p = ws + off;
        off += (bytes + 255) & ~(size_t)255;
        return p;
    };
    const size_t hbytes = (size_t)N_EDGES * HID;                 // 102.4 MB fp8
    u8* h0 = (u8*)alloc(hbytes);
    u8* hA = (u8*)alloc(hbytes);
    u8* hB = (u8*)alloc(hbytes);
    u8* node_sum = (u8*)alloc((size_t)N_NODES * HID);            // 25.6 MB fp8
    int* row_ptr = (int*)alloc((size_t)(N_NODES + 1) * sizeof(int));
    int* eidx = (int*)alloc((size_t)N_EDGES * sizeof(int));
    int* src_d = (int*)alloc((size_t)N_EDGES * sizeof(int));
    int* rev_d = (int*)alloc((size_t)N_EDGES * sizeof(int));
    u16* ea_d = (u16*)alloc((size_t)N_EDGES * 16 * sizeof(u16));  // 25.6 MB
    u16* WT1 = (u16*)alloc((size_t)HID * K1_STRIDE * sizeof(u16));
    u16* WT2 = (u16*)alloc((size_t)HID * K2_STRIDE * sizeof(u16));
    u16* WT3 = (u16*)alloc((size_t)HID * K3_STRIDE * sizeof(u16));
    // Aliases:
    //  - xw (bf16, 51.2 MB) lives in hA: dead before the first k_msg writes hA.
    //  - node_attr (bf16, 51.2 MB) lives in h0: dead after last k_msg read.
    u16* xw = (u16*)hA;
    u16* node_attr = (u16*)h0;
    // total ~370 MB < proven ws floor of ~415.7 MB (round-3 fp8_csr tier ran)

    if (ws_size < off) return;  // diagnostic: leave d_out untouched

    // weight transpose+pad to bf16 (single launch)
    k_prep3<<<(HID * (K1_STRIDE + K2_STRIDE + K3_STRIDE) + 255) / 256, 256, 0,
              stream>>>(W1, W2, W3, WT1, WT2, WT3);

    // CSR build + dst-sorted relabeling (transients overlay node_sum, 6.4MB < 25.6MB)
    {
        int* cnt = (int*)node_sum;
        int* local = cnt + N_NODES;
        int* cursor = local + N_NODES;
        int* partial = cursor + N_NODES;
        int* inv = partial + 4096;
        hipMemsetAsync(cnt, 0, (size_t)N_NODES * sizeof(int), stream);
        k_hist<<<(N_EDGES + 255) / 256, 256, 0, stream>>>(dst, cnt);
        k_scan1<<<SCAN_NBLK, 256, 0, stream>>>(cnt, local, partial);
        k_scan2<<<1, 256, 0, stream>>>(partial);
        k_scan3<<<(N_NODES + 256) / 256, 256, 0, stream>>>(local, partial, row_ptr, cursor);
        k_place<<<(N_EDGES + 255) / 256, 256, 0, stream>>>(dst, cursor, eidx, inv);
        k_setup<<<(N_EDGES + 255) / 256, 256, 0, stream>>>(eidx, src, rev, inv, ea, src_d, rev_d, ea_d);
    }

    // h0 = relu(x[src]@W1x + ea@W1e + b1)
    k_xw<<<N_NODES / MT, 256, 0, stream>>>(x, WT1, xw);
    k_init3<<<N_EDGES / MT, 256, 0, stream>>>(xw, ea_d, WT1, b1, src_d, h0);

    const u8* h = h0;
    u8* bufs[2] = {hA, hB};
    const int agg_blocks = (int)(((long long)N_NODES * 8 + 255) / 256);
    for (int it = 0; it < 3; it++) {
        k_gather<<<agg_blocks, 256, 0, stream>>>(h, row_ptr, node_sum);
        u8* hn = bufs[it & 1];   // it0 writes hA (xw already consumed)
        k_msg_mfma<<<N_EDGES / MT2, 512, 0, stream>>>(node_sum, h, h0, WT2, b2, src_d, rev_d, hn);
        h = hn;
    }

    // h0 is dead from here (final h = hA); node_attr reuses h0's storage.
    // k_node fuses the final aggregation (reads h rows via row_ptr directly).
    k_node_mfma<<<N_NODES / MT, 512, 0, stream>>>(x, hA, row_ptr, WT3, b3, node_attr);
    k_pool2<<<NUM_GRAPHS, 128, 0, stream>>>(node_attr, bat, (float*)d_out);
}

// Round 24
// 813.194 us; speedup vs baseline: 1.0763x; 1.0763x over previous
//
#include <hip/hip_runtime.h>

#define N_NODES 200000
#define N_EDGES 800000
#define NODE_IN 133
#define EDGE_IN 14
#define HID 128
#define NUM_GRAPHS 4096

#define SCAN_CHUNK 2048
#define SCAN_NBLK ((N_NODES + SCAN_CHUNK - 1) / SCAN_CHUNK)  // 98

#define MT 64    // M tile rows for k_xw/k_init3/k_node
#define MT2 128  // M tile rows for k_msg (512 threads, 8 waves)

// K geometry per GEMM (padded K, LDS/WT row stride in elements)
#define K1_PAD 160
#define K1_STRIDE 168
#define K2_PAD 128
#define K2_STRIDE 136
#define K3_PAD 288
#define K3_STRIDE 296    // WT3 global row stride == k_node LDS stride
#define KE_PAD 32        // k_init3 ea K (14 used, zero-padded)
#define KE_STRIDE 40

typedef unsigned short u16;
typedef unsigned char u8;
typedef short bf16x8 __attribute__((ext_vector_type(8)));
typedef float f32x4 __attribute__((ext_vector_type(4)));

__device__ __forceinline__ float bu2f(unsigned s) {
    return __uint_as_float(s << 16);
}
__device__ __forceinline__ u16 f2bu(float f) {
    unsigned u = __float_as_uint(f);
    return (u16)((u + 0x7FFFu + ((u >> 16) & 1u)) >> 16);  // RNE
}
// truncating f32->bf16 (1 op). Use ONLY where inputs are already fp8-coarse.
__device__ __forceinline__ u16 f2bt(float f) {
    return (u16)(__float_as_uint(f) >> 16);
}
// ---------------- fp8 e4m3 (OCP), non-negative post-ReLU values -----------
__device__ __forceinline__ float e42f(unsigned b) {
    unsigned E = (b >> 4) & 0xF, M = b & 7u;
    if (E == 0) return (float)M * 0.001953125f;  // M * 2^-9
    return __uint_as_float(((E - 7u + 127u) << 23) | (M << 20));
}
__device__ __forceinline__ u8 f2e4(float f) {
    if (!(f > 0.f)) return 0;
    if (f >= 448.f) return 0x7E;
    unsigned u = __float_as_uint(f);
    int e = (int)((u >> 23) & 0xFF) - 127;
    if (e < -6) {
        int q = (int)rintf(f * 512.f);
        return (u8)q;
    }
    unsigned m = u & 0x7FFFFF;
    unsigned keep = m >> 20, rem = m & 0xFFFFF;
    keep += (rem > 0x80000u || (rem == 0x80000u && (keep & 1u))) ? 1u : 0u;
    unsigned E = (unsigned)(e + 7);
    if (keep == 8u) { keep = 0u; E++; }
    return (u8)((E << 4) | keep);
}

// ---------------- HW fp8 convert (gfx950 OCP) with software fallback -------
#if defined(__has_builtin)
#if __has_builtin(__builtin_amdgcn_cvt_f32_fp8) && __has_builtin(__builtin_amdgcn_cvt_pk_fp8_f32)
#define HW_FP8 1
#endif
#endif

#if defined(HW_FP8)
// sel must be a compile-time constant
#define FP8_DEC(dw, s) __builtin_amdgcn_cvt_f32_fp8((int)(dw), (s))
__device__ __forceinline__ unsigned fp8_pk(float a, float b) {
    a = fminf(fmaxf(a, 0.f), 448.f);  // ReLU + sat (matches sw path)
    b = fminf(fmaxf(b, 0.f), 448.f);
    return (unsigned)__builtin_amdgcn_cvt_pk_fp8_f32(a, b, 0, false) & 0xFFFFu;
}
#else
#define FP8_DEC(dw, s) e42f(((dw) >> (8 * (s))) & 0xFFu)
__device__ __forceinline__ unsigned fp8_pk(float a, float b) {
    return (unsigned)f2e4(a) | ((unsigned)f2e4(b) << 8);
}
#endif

__device__ __forceinline__ int clampi(int v, int hi) {
    return v < 0 ? 0 : (v >= hi ? hi - 1 : v);
}

__device__ __forceinline__ void acc16(float* a, const uint4 v) {
    a[0]  += FP8_DEC(v.x, 0); a[1]  += FP8_DEC(v.x, 1);
    a[2]  += FP8_DEC(v.x, 2); a[3]  += FP8_DEC(v.x, 3);
    a[4]  += FP8_DEC(v.y, 0); a[5]  += FP8_DEC(v.y, 1);
    a[6]  += FP8_DEC(v.y, 2); a[7]  += FP8_DEC(v.y, 3);
    a[8]  += FP8_DEC(v.z, 0); a[9]  += FP8_DEC(v.z, 1);
    a[10] += FP8_DEC(v.z, 2); a[11] += FP8_DEC(v.z, 3);
    a[12] += FP8_DEC(v.w, 0); a[13] += FP8_DEC(v.w, 1);
    a[14] += FP8_DEC(v.w, 2); a[15] += FP8_DEC(v.w, 3);
}

// ---------------------------------------------------------------------------
// Weight prep (single launch): WT[n][k] = bf16(W[k][n]), k < K else 0.
// ---------------------------------------------------------------------------
__global__ __launch_bounds__(256) void k_prep3(const float* __restrict__ W1,
                                               const float* __restrict__ W2,
                                               const float* __restrict__ W3,
                                               u16* __restrict__ WT1,
                                               u16* __restrict__ WT2,
                                               u16* __restrict__ WT3) {
    int idx = blockIdx.x * 256 + threadIdx.x;
    const int n1 = HID * K1_STRIDE, n2 = HID * K2_STRIDE, n3 = HID * K3_STRIDE;
    if (idx < n1) {
        const int n = idx / K1_STRIDE, k = idx % K1_STRIDE;
        WT1[idx] = (k < NODE_IN + EDGE_IN) ? f2bu(W1[k * HID + n]) : (u16)0;
    } else if ((idx -= n1) < n2) {
        const int n = idx / K2_STRIDE, k = idx % K2_STRIDE;
        WT2[idx] = (k < HID) ? f2bu(W2[k * HID + n]) : (u16)0;
    } else if ((idx -= n2) < n3) {
        const int n = idx / K3_STRIDE, k = idx % K3_STRIDE;
        WT3[idx] = (k < NODE_IN + HID) ? f2bu(W3[k * HID + n]) : (u16)0;
    }
}

// ---------------------------------------------------------------------------
// CSR build: histogram -> exclusive scan -> atomic-cursor placement.
// Edge state space is RELABELED into dst-sorted order: j <-> eidx[j].
// ---------------------------------------------------------------------------
__global__ __launch_bounds__(256) void k_hist(const int* __restrict__ dst,
                                              int* __restrict__ cnt) {
    const int e = blockIdx.x * 256 + threadIdx.x;
    if (e < N_EDGES) atomicAdd(&cnt[clampi(dst[e], N_NODES)], 1);
}

__global__ __launch_bounds__(256) void k_scan1(const int* __restrict__ cnt,
                                               int* __restrict__ local,
                                               int* __restrict__ partial) {
    __shared__ int tsum[256];
    const int b = blockIdx.x, t = threadIdx.x;
    const int base = b * SCAN_CHUNK + t * 8;
    int v[8];
    int s = 0;
#pragma unroll
    for (int i = 0; i < 8; i++) {
        const int idx = base + i;
        v[i] = (idx < N_NODES) ? cnt[idx] : 0;
        s += v[i];
    }
    tsum[t] = s;
    __syncthreads();
    for (int ofs = 1; ofs < 256; ofs <<= 1) {
        const int add = (t >= ofs) ? tsum[t - ofs] : 0;
        __syncthreads();
        tsum[t] += add;
        __syncthreads();
    }
    int excl = (t == 0) ? 0 : tsum[t - 1];
    if (t == 255) partial[b] = tsum[255];
#pragma unroll
    for (int i = 0; i < 8; i++) {
        const int idx = base + i;
        if (idx < N_NODES) local[idx] = excl;
        excl += v[i];
    }
}

__global__ __launch_bounds__(256) void k_scan2(int* __restrict__ partial) {
    __shared__ int s[256];
    const int t = threadIdx.x;
    s[t] = (t < SCAN_NBLK) ? partial[t] : 0;
    __syncthreads();
    for (int ofs = 1; ofs < 256; ofs <<= 1) {
        const int add = (t >= ofs) ? s[t - ofs] : 0;
        __syncthreads();
        s[t] += add;
        __syncthreads();
    }
    if (t < SCAN_NBLK) partial[t] = (t == 0) ? 0 : s[t - 1];
}

__global__ __launch_bounds__(256) void k_scan3(const int* __restrict__ local,
                                               const int* __restrict__ partial,
                                               int* __restrict__ row_ptr,
                                               int* __restrict__ cursor) {
    const int idx = blockIdx.x * 256 + threadIdx.x;
    if (idx <= N_NODES) {
        const int v = (idx == N_NODES) ? N_EDGES
                                       : local[idx] + partial[idx / SCAN_CHUNK];
        row_ptr[idx] = v;
        if (idx < N_NODES) cursor[idx] = v;
    }
}

// placement + inverse permutation in one pass
__global__ __launch_bounds__(256) void k_place(const int* __restrict__ dst,
                                               int* __restrict__ cursor,
                                               int* __restrict__ eidx,
                                               int* __restrict__ inv) {
    const int e = blockIdx.x * 256 + threadIdx.x;
    if (e < N_EDGES) {
        const int slot = atomicAdd(&cursor[clampi(dst[e], N_NODES)], 1);
        eidx[slot] = e;
        inv[e] = slot;
    }
}

// merged remap + ea pack: one eidx read per sorted edge
__global__ __launch_bounds__(256) void k_setup(const int* __restrict__ eidx,
                                               const int* __restrict__ src,
                                               const int* __restrict__ rev,
                                               const int* __restrict__ inv,
                                               const float* __restrict__ ea,
                                               int* __restrict__ src_d,
                                               int* __restrict__ rev_d,
                                               u16* __restrict__ ea_d) {
    const int j = blockIdx.x * 256 + threadIdx.x;
    if (j >= N_EDGES) return;
    const int e = clampi(eidx[j], N_EDGES);
    src_d[j] = src[e];
    rev_d[j] = inv[clampi(rev[e], N_EDGES)];
    const float2* er = (const float2*)(ea + (size_t)e * EDGE_IN);
    u16 v[16];
#pragma unroll
    for (int k = 0; k < 7; k++) {
        const float2 u = er[k];
        v[2 * k] = f2bu(u.x);
        v[2 * k + 1] = f2bu(u.y);
    }
    v[14] = 0; v[15] = 0;
    uint4 o1, o2;
    o1.x = (unsigned)v[0] | ((unsigned)v[1] << 16);
    o1.y = (unsigned)v[2] | ((unsigned)v[3] << 16);
    o1.z = (unsigned)v[4] | ((unsigned)v[5] << 16);
    o1.w = (unsigned)v[6] | ((unsigned)v[7] << 16);
    o2.x = (unsigned)v[8] | ((unsigned)v[9] << 16);
    o2.y = (unsigned)v[10] | ((unsigned)v[11] << 16);
    o2.z = (unsigned)v[12] | ((unsigned)v[13] << 16);
    o2.w = 0;
    uint4* dstp = (uint4*)(ea_d + (size_t)j * 16);
    dstp[0] = o1;
    dstp[1] = o2;
}

// ---------------------------------------------------------------------------
// K2 (streaming gather): node_sum[n] (fp8) = sum over contiguous sorted rows.
// 8 threads/node, 16 channels each (uint4 loads), 4-deep unrolled deg loop.
// ---------------------------------------------------------------------------
__global__ __launch_bounds__(256) void k_gather(const u8* __restrict__ h,
                                                const int* __restrict__ row_ptr,
                                                u8* __restrict__ node_sum) {
    const long long idx = (long long)blockIdx.x * 256 + threadIdx.x;
    const int n = (int)(idx >> 3);
    if (n >= N_NODES) return;
    const int c16 = (int)(idx & 7) << 4;
    const int beg = row_ptr[n], end = row_ptr[n + 1];
    float a[16];
#pragma unroll
    for (int i = 0; i < 16; i++) a[i] = 0.f;
    int j = beg;
    for (; j + 4 <= end; j += 4) {
        const uint4 v0 = *(const uint4*)(h + (long long)j * HID + c16);
        const uint4 v1 = *(const uint4*)(h + (long long)(j + 1) * HID + c16);
        const uint4 v2 = *(const uint4*)(h + (long long)(j + 2) * HID + c16);
        const uint4 v3 = *(const uint4*)(h + (long long)(j + 3) * HID + c16);
        acc16(a, v0); acc16(a, v1); acc16(a, v2); acc16(a, v3);
    }
    for (; j < end; j++) {
        const uint4 v = *(const uint4*)(h + (long long)j * HID + c16);
        acc16(a, v);
    }
    uint4 o;
    o.x = fp8_pk(a[0], a[1])   | (fp8_pk(a[2], a[3])   << 16);
    o.y = fp8_pk(a[4], a[5])   | (fp8_pk(a[6], a[7])   << 16);
    o.z = fp8_pk(a[8], a[9])   | (fp8_pk(a[10], a[11]) << 16);
    o.w = fp8_pk(a[12], a[13]) | (fp8_pk(a[14], a[15]) << 16);
    *(uint4*)(node_sum + (long long)n * HID + c16) = o;
}

// ---------------------------------------------------------------------------
// MFMA geometry: a-frag lane holds A[lane&15][(lane>>4)*8 + i];
// C/D: col = lane&15, row = (lane>>4)*4 + reg.
// k_xw/k_init3: 4 waves (2Mx2N). k_msg: 8 waves (4Mx2N), 128-row tiles.
// k_node: 8 waves (2Mx4N), fused final aggregation.
// ---------------------------------------------------------------------------

// K1a: xw[n] = x[n] @ W1x  (per-NODE GEMM; A cols 133..159 zeroed)
__global__ __launch_bounds__(256) void k_xw(const float* __restrict__ x,
                                            const u16* __restrict__ WT1,
                                            u16* __restrict__ xw) {
    __shared__ u16 A[MT * K1_STRIDE];
    const int n0 = blockIdx.x * MT;
    const int t = threadIdx.x;
    const int lane = t & 63, wv = t >> 6;
    for (int rr = 0; rr < 16; rr++) {
        const int row = wv * 16 + rr;
        const int n = n0 + row;
        const float* xr = x + (size_t)n * NODE_IN;
        u16* dstr = &A[row * K1_STRIDE];
        dstr[lane] = f2bu(xr[lane]);                 // k 0..63
        dstr[64 + lane] = f2bu(xr[64 + lane]);       // k 64..127
        if (lane < 5) dstr[128 + lane] = f2bu(xr[128 + lane]);  // 128..132
        if (lane < K1_PAD - NODE_IN) dstr[NODE_IN + lane] = 0;  // 133..159
    }
    __syncthreads();

    const int wm = wv & 1, wn = wv >> 1;
    const int lr = lane & 15, lk = (lane >> 4) * 8;
    f32x4 acc[2][4];
#pragma unroll
    for (int m = 0; m < 2; m++)
#pragma unroll
        for (int n = 0; n < 4; n++) acc[m][n] = (f32x4){0.f, 0.f, 0.f, 0.f};

    const int ar0 = (wm * 32 + lr) * K1_STRIDE + lk;
#pragma unroll
    for (int ks = 0; ks < K1_PAD / 32; ks++) {
        const int kk = ks * 32;
        const bf16x8 a0 = *(const bf16x8*)&A[ar0 + kk];
        const bf16x8 a1 = *(const bf16x8*)&A[ar0 + 16 * K1_STRIDE + kk];
#pragma unroll
        for (int n = 0; n < 4; n++) {
            const bf16x8 b = *(const bf16x8*)&WT1[(size_t)(wn * 64 + n * 16 + lr) * K1_STRIDE + kk + lk];
            acc[0][n] = __builtin_amdgcn_mfma_f32_16x16x32_bf16(a0, b, acc[0][n], 0, 0, 0);
            acc[1][n] = __builtin_amdgcn_mfma_f32_16x16x32_bf16(a1, b, acc[1][n], 0, 0, 0);
        }
    }

    const int lr4 = lane >> 4;
#pragma unroll
    for (int n = 0; n < 4; n++) {
        const int col = wn * 64 + n * 16 + lr;
#pragma unroll
        for (int m = 0; m < 2; m++)
#pragma unroll
            for (int j = 0; j < 4; j++) {
                const int nd = n0 + wm * 32 + m * 16 + lr4 * 4 + j;
                xw[(size_t)nd * HID + col] = f2bu(acc[m][n][j]);
            }
    }
}

// K1b (MFMA): h0[j] = relu(xw[src_d[j]] + ea_d[j]@W1e + b1) -> fp8.
// ea matvec on the matrix pipe; xw row PREFETCHED; W1e staged from WT1.
__global__ __launch_bounds__(256) void k_init3(const u16* __restrict__ xw,
                                               const u16* __restrict__ ea_d,
                                               const u16* __restrict__ WT1,
                                               const float* __restrict__ b1,
                                               const int* __restrict__ src_d,
                                               u8* __restrict__ h0) {
    __shared__ u16 Aea[MT * KE_STRIDE];       // 5120 B
    __shared__ u16 W1e[HID * KE_PAD];         // [n][k], 8192 B
    __shared__ u16 Sacc[MT * K2_STRIDE];      // 17408 B staging
    __shared__ float b1s[HID];
    const int e0 = blockIdx.x * MT;
    const int t = threadIdx.x;

    // prefetch phase-2 operands (consumed after 2 barriers)
    const int prow = t >> 2, pj = t & 3;
    const int ps = clampi(src_d[e0 + prow], N_NODES);
    uint4 xv[4];
#pragma unroll
    for (int q = 0; q < 4; q++)
        xv[q] = *(const uint4*)(xw + (size_t)ps * HID + pj * 32 + q * 8);

    for (int i = t; i < HID * KE_PAD; i += 256) {
        const int n = i >> 5, k = i & 31;
        W1e[i] = (k < EDGE_IN) ? WT1[n * K1_STRIDE + NODE_IN + k] : (u16)0;
    }
    if (t < HID) b1s[t] = b1[t];
    {   // ea tile: 4 threads/row, 8B each; pad 16..31 zeroed
        const int row = t >> 2, q = t & 3;
        const uint2 v = *(const uint2*)(ea_d + (size_t)(e0 + row) * 16 + q * 4);
        *(uint2*)&Aea[row * KE_STRIDE + q * 4] = v;
        uint2 z; z.x = 0; z.y = 0;
        *(uint2*)&Aea[row * KE_STRIDE + 16 + q * 4] = z;
    }
    __syncthreads();

    const int lane = t & 63, wid = t >> 6;
    const int wm = wid & 1, wn = wid >> 1;
    const int lr = lane & 15, lk = (lane >> 4) * 8;
    f32x4 acc[2][4];
#pragma unroll
    for (int m = 0; m < 2; m++)
#pragma unroll
        for (int n = 0; n < 4; n++) acc[m][n] = (f32x4){0.f, 0.f, 0.f, 0.f};

    {
        const bf16x8 a0 = *(const bf16x8*)&Aea[(wm * 32 + lr) * KE_STRIDE + lk];
        const bf16x8 a1 = *(const bf16x8*)&Aea[(wm * 32 + 16 + lr) * KE_STRIDE + lk];
#pragma unroll
        for (int n = 0; n < 4; n++) {
            const bf16x8 b = *(const bf16x8*)&W1e[(wn * 64 + n * 16 + lr) * KE_PAD + lk];
            acc[0][n] = __builtin_amdgcn_mfma_f32_16x16x32_bf16(a0, b, acc[0][n], 0, 0, 0);
            acc[1][n] = __builtin_amdgcn_mfma_f32_16x16x32_bf16(a1, b, acc[1][n], 0, 0, 0);
        }
    }

    // stage product bf16 -> Sacc[row][col]
    const int lr4 = lane >> 4;
#pragma unroll
    for (int n = 0; n < 4; n++) {
        const int col = wn * 64 + n * 16 + lr;
#pragma unroll
        for (int m = 0; m < 2; m++)
#pragma unroll
            for (int j = 0; j < 4; j++) {
                const int row = wm * 32 + m * 16 + lr4 * 4 + j;
                Sacc[row * K2_STRIDE + col] = f2bu(acc[m][n][j]);
            }
    }
    __syncthreads();

    // phase 2: coalesced, thread = (row, 32-ch chunk)
    const long long e = e0 + prow;
#pragma unroll
    for (int q = 0; q < 4; q++) {
        const int c8 = pj * 32 + q * 8;
        const uint4 sv = *(const uint4*)&Sacc[prow * K2_STRIDE + c8];  // 8 bf16
        const float4 ba = *(const float4*)&b1s[c8];
        const float4 bbv = *(const float4*)&b1s[c8 + 4];
        const float v0 = bu2f(sv.x & 0xFFFFu) + bu2f(xv[q].x & 0xFFFFu) + ba.x;
        const float v1 = bu2f(sv.x >> 16)     + bu2f(xv[q].x >> 16)     + ba.y;
        const float v2 = bu2f(sv.y & 0xFFFFu) + bu2f(xv[q].y & 0xFFFFu) + ba.z;
        const float v3 = bu2f(sv.y >> 16)     + bu2f(xv[q].y >> 16)     + ba.w;
        const float v4 = bu2f(sv.z & 0xFFFFu) + bu2f(xv[q].z & 0xFFFFu) + bbv.x;
        const float v5 = bu2f(sv.z >> 16)     + bu2f(xv[q].z >> 16)     + bbv.y;
        const float v6 = bu2f(sv.w & 0xFFFFu) + bu2f(xv[q].w & 0xFFFFu) + bbv.z;
        const float v7 = bu2f(sv.w >> 16)     + bu2f(xv[q].w >> 16)     + bbv.w;
        uint2 o;
        o.x = fp8_pk(v0, v1) | (fp8_pk(v2, v3) << 16);
        o.y = fp8_pk(v4, v5) | (fp8_pk(v6, v7) << 16);
        *(uint2*)(h0 + e * HID + c8) = o;
    }
}

// K3: hn[j] = relu(h0[j] + (node_sum[src_d[j]] - h[rev_d[j]]) @ W2 + b2)
// 512 threads, 8 waves (4M x 2N), 128-edge tile. ns is fp8; h0 prefetched;
// m/product staging uses truncating bf16 pack (inputs fp8-coarse).
__global__ __launch_bounds__(512) void k_msg_mfma(const u8* __restrict__ ns,
                                                  const u8* __restrict__ h,
                                                  const u8* __restrict__ h0g,
                                                  const u16* __restrict__ WT2,
                                                  const float* __restrict__ b2,
                                                  const int* __restrict__ src_d,
                                                  const int* __restrict__ rev_d,
                                                  u8* __restrict__ hn) {
    __shared__ u16 A[MT2 * K2_STRIDE];  // 34816 B
    __shared__ float b2s[HID];
    const int e0 = blockIdx.x * MT2;
    const int t = threadIdx.x;

    // prefetch phase-2 h0 row chunks (stream; consumed after 2 barriers)
    const int prow = t >> 2, pj = t & 3;   // prow 0..127
    const long long pe = e0 + prow;
    uint2 h0v[4];
#pragma unroll
    for (int q = 0; q < 4; q++)
        h0v[q] = *(const uint2*)(h0g + pe * HID + pj * 32 + q * 8);

    if (t < HID) b2s[t] = b2[t];
    {   // builder: 4 threads/row, 32 channels each (all fp8 inputs)
        const int s = clampi(src_d[e0 + prow], N_NODES);
        const int r = clampi(rev_d[e0 + prow], N_EDGES);
        const u8* nsr = ns + (size_t)s * HID + pj * 32;
        const u8* hr = h + (size_t)r * HID + pj * 32;
        u16* dstr = &A[prow * K2_STRIDE + pj * 32];
#pragma unroll
        for (int q = 0; q < 4; q++) {
            const uint2 nv = *(const uint2*)(nsr + q * 8);  // 8 fp8
            const uint2 hv = *(const uint2*)(hr + q * 8);   // 8 fp8
            union { bf16x8 v; u16 s[8]; } o;
            o.s[0] = f2bt(FP8_DEC(nv.x, 0) - FP8_DEC(hv.x, 0));
            o.s[1] = f2bt(FP8_DEC(nv.x, 1) - FP8_DEC(hv.x, 1));
            o.s[2] = f2bt(FP8_DEC(nv.x, 2) - FP8_DEC(hv.x, 2));
            o.s[3] = f2bt(FP8_DEC(nv.x, 3) - FP8_DEC(hv.x, 3));
            o.s[4] = f2bt(FP8_DEC(nv.y, 0) - FP8_DEC(hv.y, 0));
            o.s[5] = f2bt(FP8_DEC(nv.y, 1) - FP8_DEC(hv.y, 1));
            o.s[6] = f2bt(FP8_DEC(nv.y, 2) - FP8_DEC(hv.y, 2));
            o.s[7] = f2bt(FP8_DEC(nv.y, 3) - FP8_DEC(hv.y, 3));
            *(bf16x8*)(dstr + q * 8) = o.v;
        }
    }
    __syncthreads();

    const int lane = t & 63, wid = t >> 6;   // 8 waves
    const int wm = wid & 3, wn = wid >> 2;   // 4 in M, 2 in N
    const int lr = lane & 15, lk = (lane >> 4) * 8;
    f32x4 acc[2][4];
#pragma unroll
    for (int m = 0; m < 2; m++)
#pragma unroll
        for (int n = 0; n < 4; n++) acc[m][n] = (f32x4){0.f, 0.f, 0.f, 0.f};

    const int ar0 = (wm * 32 + lr) * K2_STRIDE + lk;
#pragma unroll
    for (int ks = 0; ks < K2_PAD / 32; ks++) {
        const int kk = ks * 32;
        const bf16x8 a0 = *(const bf16x8*)&A[ar0 + kk];
        const bf16x8 a1 = *(const bf16x8*)&A[ar0 + 16 * K2_STRIDE + kk];
#pragma unroll
        for (int n = 0; n < 4; n++) {
            const bf16x8 b = *(const bf16x8*)&WT2[(size_t)(wn * 64 + n * 16 + lr) * K2_STRIDE + kk + lk];
            acc[0][n] = __builtin_amdgcn_mfma_f32_16x16x32_bf16(a0, b, acc[0][n], 0, 0, 0);
            acc[1][n] = __builtin_amdgcn_mfma_f32_16x16x32_bf16(a1, b, acc[1][n], 0, 0, 0);
        }
    }

    __syncthreads();  // A's builder data fully consumed
    const int lr4 = lane >> 4;
#pragma unroll
    for (int n = 0; n < 4; n++) {
        const int col = wn * 64 + n * 16 + lr;
#pragma unroll
        for (int m = 0; m < 2; m++)
#pragma unroll
            for (int j = 0; j < 4; j++) {
                const int row = wm * 32 + m * 16 + lr4 * 4 + j;
                A[row * K2_STRIDE + col] = f2bt(acc[m][n][j]);
            }
    }
    __syncthreads();

#pragma unroll
    for (int q = 0; q < 4; q++) {
        const int c8 = pj * 32 + q * 8;
        const uint4 sv = *(const uint4*)&A[prow * K2_STRIDE + c8];  // 8 bf16
        const float4 ba = *(const float4*)&b2s[c8];
        const float4 bbv = *(const float4*)&b2s[c8 + 4];
        const float v0 = bu2f(sv.x & 0xFFFFu) + FP8_DEC(h0v[q].x, 0) + ba.x;
        const float v1 = bu2f(sv.x >> 16)     + FP8_DEC(h0v[q].x, 1) + ba.y;
        const float v2 = bu2f(sv.y & 0xFFFFu) + FP8_DEC(h0v[q].x, 2) + ba.z;
        const float v3 = bu2f(sv.y >> 16)     + FP8_DEC(h0v[q].x, 3) + ba.w;
        const float v4 = bu2f(sv.z & 0xFFFFu) + FP8_DEC(h0v[q].y, 0) + bbv.x;
        const float v5 = bu2f(sv.z >> 16)     + FP8_DEC(h0v[q].y, 1) + bbv.y;
        const float v6 = bu2f(sv.w & 0xFFFFu) + FP8_DEC(h0v[q].y, 2) + bbv.z;
        const float v7 = bu2f(sv.w >> 16)     + FP8_DEC(h0v[q].y, 3) + bbv.w;
        uint2 o;
        o.x = fp8_pk(v0, v1) | (fp8_pk(v2, v3) << 16);
        o.y = fp8_pk(v4, v5) | (fp8_pk(v6, v7) << 16);
        *(uint2*)(hn + pe * HID + c8) = o;
    }
}

// K5 (FUSED final aggregation + node GEMM):
// node_attr[n] = relu(concat(x[n], sum_{j in csr[n]} h[j]) @ W3 + b3)
// 512 threads, 8 waves (2M x 4N), single-phase full-K tile (64 x 296 LDS).
__global__ __launch_bounds__(512) void k_node_mfma(const float* __restrict__ x,
                                                   const u8* __restrict__ h,
                                                   const int* __restrict__ row_ptr,
                                                   const u16* __restrict__ WT3,
                                                   const float* __restrict__ b3,
                                                   u16* __restrict__ node_attr) {
    __shared__ u16 A[MT * K3_STRIDE];  // 37888 B
    const int n0 = blockIdx.x * MT;
    const int t = threadIdx.x;
    const int lane = t & 63, wv = t >> 6;       // 8 waves
    const int wm = wv & 1, wn = wv >> 1;        // 2 in M, 4 in N
    const int lr = lane & 15, lk = (lane >> 4) * 8;

    {   // phase A: vmsg summation (fused gather). lane = sub-node*8 + chunk
        const int vrow = wv * 8 + (lane >> 3);
        const int vn = n0 + vrow;
        const int c16 = (lane & 7) << 4;
        const int beg = row_ptr[vn], end = row_ptr[vn + 1];
        float a[16];
#pragma unroll
        for (int i = 0; i < 16; i++) a[i] = 0.f;
        int j = beg;
        for (; j + 4 <= end; j += 4) {
            const uint4 v0 = *(const uint4*)(h + (long long)j * HID + c16);
            const uint4 v1 = *(const uint4*)(h + (long long)(j + 1) * HID + c16);
            const uint4 v2 = *(const uint4*)(h + (long long)(j + 2) * HID + c16);
            const uint4 v3 = *(const uint4*)(h + (long long)(j + 3) * HID + c16);
            acc16(a, v0); acc16(a, v1); acc16(a, v2); acc16(a, v3);
        }
        for (; j < end; j++) {
            const uint4 v = *(const uint4*)(h + (long long)j * HID + c16);
            acc16(a, v);
        }
        u16* vd = &A[vrow * K3_STRIDE + NODE_IN + c16];  // cols 133..260
#pragma unroll
        for (int i = 0; i < 16; i++) vd[i] = f2bt(a[i]);
    }

    // phase B: x columns + zero pad (8 rows per wave, 64 lanes)
    for (int rr = 0; rr < 8; rr++) {
        const int row = wv * 8 + rr;
        const int n = n0 + row;
        const float* xr = x + (size_t)n * NODE_IN;
        u16* dstr = &A[row * K3_STRIDE];
        dstr[lane] = f2bu(xr[lane]);                 // k 0..63
        dstr[64 + lane] = f2bu(xr[64 + lane]);       // k 64..127
        if (lane < 5) dstr[128 + lane] = f2bu(xr[128 + lane]);  // 128..132
        if (lane < K3_PAD - (NODE_IN + HID))         // 261..287
            dstr[NODE_IN + HID + lane] = 0;
    }
    __syncthreads();

    f32x4 acc[2][2];
#pragma unroll
    for (int m = 0; m < 2; m++)
#pragma unroll
        for (int n = 0; n < 2; n++) acc[m][n] = (f32x4){0.f, 0.f, 0.f, 0.f};
    const int ar0 = (wm * 32 + lr) * K3_STRIDE + lk;

    for (int ks = 0; ks < K3_PAD / 32; ks++) {       // 9 steps
        const int kk = ks * 32;
        const bf16x8 a0 = *(const bf16x8*)&A[ar0 + kk];
        const bf16x8 a1 = *(const bf16x8*)&A[ar0 + 16 * K3_STRIDE + kk];
#pragma unroll
        for (int n = 0; n < 2; n++) {
            const bf16x8 b = *(const bf16x8*)&WT3[(size_t)(wn * 32 + n * 16 + lr) * K3_STRIDE + kk + lk];
            acc[0][n] = __builtin_amdgcn_mfma_f32_16x16x32_bf16(a0, b, acc[0][n], 0, 0, 0);
            acc[1][n] = __builtin_amdgcn_mfma_f32_16x16x32_bf16(a1, b, acc[1][n], 0, 0, 0);
        }
    }

    const int lr4 = lane >> 4;
#pragma unroll
    for (int n = 0; n < 2; n++) {
        const int col = wn * 32 + n * 16 + lr;
        const float bias = b3[col];
#pragma unroll
        for (int m = 0; m < 2; m++)
#pragma unroll
            for (int j = 0; j < 4; j++) {
                const int nd = n0 + wm * 32 + m * 16 + lr4 * 4 + j;
                float v = acc[m][n][j] + bias;
                node_attr[(size_t)nd * HID + col] = f2bu(v > 0.f ? v : 0.f);
            }
    }
}

// ---------------------------------------------------------------------------
// K6: out[g] = mean over the graph's contiguous node range (bf16 node_attr).
// ---------------------------------------------------------------------------
__global__ __launch_bounds__(128) void k_pool2(const u16* __restrict__ node_attr,
                                               const int* __restrict__ batch,
                                               float* __restrict__ out) {
    const int g = blockIdx.x;
    __shared__ int lo_s, hi_s;
    if (threadIdx.x == 0) {
        int lo = 0, hi = N_NODES;
        while (lo < hi) { int mid = (lo + hi) >> 1; if (batch[mid] < g) lo = mid + 1; else hi = mid; }
        lo_s = lo;
        int lo2 = lo, hi2 = N_NODES;
        while (lo2 < hi2) { int mid = (lo2 + hi2) >> 1; if (batch[mid] <= g) lo2 = mid + 1; else hi2 = mid; }
        hi_s = lo2;
    }
    __syncthreads();
    const int lo = lo_s, hi = hi_s;
    float acc = 0.f;
    for (int n = lo; n < hi; n++)
        acc += bu2f(node_attr[(size_t)n * HID + threadIdx.x]);
    const float cnt = (hi > lo) ? (float)(hi - lo) : 1.f;
    out[(size_t)g * HID + threadIdx.x] = acc / cnt;
}

// ---------------------------------------------------------------------------
extern "C" void kernel_launch(void* const* d_in, const int* in_sizes, int n_in,
                              void* d_out, int out_size, void* d_ws, size_t ws_size,
                              hipStream_t stream) {
    const float* x   = (const float*)d_in[0];
    const float* ea  = (const float*)d_in[1];
    const float* W1  = (const float*)d_in[2];
    const float* b1  = (const float*)d_in[3];
    const float* W2  = (const float*)d_in[4];
    const float* b2  = (const float*)d_in[5];
    const float* W3  = (const float*)d_in[6];
    const float* b3  = (const float*)d_in[7];
    const int*   ei  = (const int*)d_in[8];
    const int*   src = ei;
    const int*   dst = ei + N_EDGES;
    const int*   rev = (const int*)d_in[9];
    const int*   bat = (const int*)d_in[10];

    char* ws = (char*)d_ws;
    size_t off = 0;
    auto alloc = [&](size_t bytes) -> void* {
        void* p = ws + off;
        off += (bytes + 255) & ~(size_t)255;
        return p;
    };
    const size_t hbytes = (size_t)N_EDGES * HID;                 // 102.4 MB fp8
    u8* h0 = (u8*)alloc(hbytes);
    u8* hA = (u8*)alloc(hbytes);
    u8* hB = (u8*)alloc(hbytes);
    u8* node_sum = (u8*)alloc((size_t)N_NODES * HID);            // 25.6 MB fp8
    int* row_ptr = (int*)alloc((size_t)(N_NODES + 1) * sizeof(int));
    int* eidx = (int*)alloc((size_t)N_EDGES * sizeof(int));
    int* src_d = (int*)alloc((size_t)N_EDGES * sizeof(int));
    int* rev_d = (int*)alloc((size_t)N_EDGES * sizeof(int));
    u16* ea_d = (u16*)alloc((size_t)N_EDGES * 16 * sizeof(u16));  // 25.6 MB
    u16* WT1 = (u16*)alloc((size_t)HID * K1_STRIDE * sizeof(u16));
    u16* WT2 = (u16*)alloc((size_t)HID * K2_STRIDE * sizeof(u16));
    u16* WT3 = (u16*)alloc((size_t)HID * K3_STRIDE * sizeof(u16));
    // Aliases:
    //  - xw (bf16, 51.2 MB) lives in hA: dead before the first k_msg writes hA.
    //  - node_attr (bf16, 51.2 MB) lives in h0: dead after last k_msg read.
    u16* xw = (u16*)hA;
    u16* node_attr = (u16*)h0;
    // total ~370 MB < proven ws floor of ~415.7 MB (round-3 fp8_csr tier ran)

    if (ws_size < off) return;  // diagnostic: leave d_out untouched

    // weight transpose+pad to bf16 (single launch)
    k_prep3<<<(HID * (K1_STRIDE + K2_STRIDE + K3_STRIDE) + 255) / 256, 256, 0,
              stream>>>(W1, W2, W3, WT1, WT2, WT3);

    // CSR build + dst-sorted relabeling (transients overlay node_sum, 6.4MB < 25.6MB)
    {
        int* cnt = (int*)node_sum;
        int* local = cnt + N_NODES;
        int* cursor = local + N_NODES;
        int* partial = cursor + N_NODES;
        int* inv = partial + 4096;
        hipMemsetAsync(cnt, 0, (size_t)N_NODES * sizeof(int), stream);
        k_hist<<<(N_EDGES + 255) / 256, 256, 0, stream>>>(dst, cnt);
        k_scan1<<<SCAN_NBLK, 256, 0, stream>>>(cnt, local, partial);
        k_scan2<<<1, 256, 0, stream>>>(partial);
        k_scan3<<<(N_NODES + 256) / 256, 256, 0, stream>>>(local, partial, row_ptr, cursor);
        k_place<<<(N_EDGES + 255) / 256, 256, 0, stream>>>(dst, cursor, eidx, inv);
        k_setup<<<(N_EDGES + 255) / 256, 256, 0, stream>>>(eidx, src, rev, inv, ea, src_d, rev_d, ea_d);
    }

    // h0 = relu(x[src]@W1x + ea@W1e + b1)
    k_xw<<<N_NODES / MT, 256, 0, stream>>>(x, WT1, xw);
    k_init3<<<N_EDGES / MT, 256, 0, stream>>>(xw, ea_d, WT1, b1, src_d, h0);

    const u8* h = h0;
    u8* bufs[2] = {hA, hB};
    const int agg_blocks = (int)(((long long)N_NODES * 8 + 255) / 256);
    for (int it = 0; it < 3; it++) {
        k_gather<<<agg_blocks, 256, 0, stream>>>(h, row_ptr, node_sum);
        u8* hn = bufs[it & 1];   // it0 writes hA (xw already consumed)
        k_msg_mfma<<<N_EDGES / MT2, 512, 0, stream>>>(node_sum, h, h0, WT2, b2, src_d, rev_d, hn);
        h = hn;
    }

    // h0 is dead from here (final h = hA); node_attr reuses h0's storage.
    // k_node fuses the final aggregation (reads h rows via row_ptr directly).
    k_node_mfma<<<N_NODES / MT, 512, 0, stream>>>(x, hA, row_ptr, WT3, b3, node_attr);
    k_pool2<<<NUM_GRAPHS, 128, 0, stream>>>(node_attr, bat, (float*)d_out);
}